// Round 9
// baseline (125.768 us; speedup 1.0000x reference)
//
#include <hip/hip_runtime.h>
#include <cmath>

#define NCH 192
#define SLAB 4096            // H*W = 64*64, elements per (b,c) row
#define LUT_N 512
#define LUT_XMIN (-8.0f)
#define LUT_H (16.0f / (float)LUT_N)     // 1/32
#define LUT_INVH ((float)LUT_N / 16.0f)  // 32.0
#define LUT_OFF (-(LUT_XMIN) * LUT_INVH) // 256.0
#define SLABS_PER_BLOCK 4

typedef float f4_t __attribute__((ext_vector_type(4)));  // native vector for NT load/store

__device__ __forceinline__ float sigmoidf_(float x) {
    return 1.0f / (1.0f + __expf(-x));
}

__device__ __forceinline__ float softplusf_(float x) {
    return (x > 20.0f) ? x : log1pf(expf(x));
}

// p layout (43 floats):
// [0:3)  sm0   [3:12) sm1   [12:21) sm2   [21:24) sm3
// [24:27) b0   [27:30) b1   [30:33) b2    [33] b3
// [34:37) tf0  [37:40) tf1  [40:43) tf2
__device__ __forceinline__ float mlp_eval(const float* __restrict__ p, float z,
                                          bool g0, bool g1, bool g2) {
    float t0 = fmaf(p[0], z, p[24]);
    float t1 = fmaf(p[1], z, p[25]);
    float t2 = fmaf(p[2], z, p[26]);
    if (g0) {
        t0 += p[34] * tanhf(t0);
        t1 += p[35] * tanhf(t1);
        t2 += p[36] * tanhf(t2);
    }
    float u0 = fmaf(p[3], t0, fmaf(p[4], t1, fmaf(p[5], t2, p[27])));
    float u1 = fmaf(p[6], t0, fmaf(p[7], t1, fmaf(p[8], t2, p[28])));
    float u2 = fmaf(p[9], t0, fmaf(p[10], t1, fmaf(p[11], t2, p[29])));
    if (g1) {
        u0 += p[37] * tanhf(u0);
        u1 += p[38] * tanhf(u1);
        u2 += p[39] * tanhf(u2);
    }
    float w0 = fmaf(p[12], u0, fmaf(p[13], u1, fmaf(p[14], u2, p[30])));
    float w1 = fmaf(p[15], u0, fmaf(p[16], u1, fmaf(p[17], u2, p[31])));
    float w2 = fmaf(p[18], u0, fmaf(p[19], u1, fmaf(p[20], u2, p[32])));
    if (g2) {
        w0 += p[40] * tanhf(w0);
        w1 += p[41] * tanhf(w1);
        w2 += p[42] * tanhf(w2);
    }
    return fmaf(p[21], w0, fmaf(p[22], w1, fmaf(p[23], w2, p[33])));
}

__device__ __forceinline__ float element(const float* __restrict__ p, float v,
                                         bool g0, bool g1, bool g2) {
    float lo = mlp_eval(p, v - 0.5f, g0, g1, g2);
    float up = mlp_eval(p, v + 0.5f, g0, g1, g2);
    float ssum = lo + up;
    float s = (ssum > 0.0f) ? -1.0f : ((ssum < 0.0f) ? 1.0f : 0.0f);
    float lk = fabsf(sigmoidf_(s * up) - sigmoidf_(s * lo));
    return fmaxf(lk, 1e-6f);
}

__device__ __forceinline__ void stage_params(
    float* p, int c, int tid,
    const float* __restrict__ m0, const float* __restrict__ b0,
    const float* __restrict__ m1, const float* __restrict__ b1,
    const float* __restrict__ m2, const float* __restrict__ b2,
    const float* __restrict__ m3, const float* __restrict__ b3,
    const float* __restrict__ f0, const float* __restrict__ f1,
    const float* __restrict__ f2)
{
    if (tid < 43) {
        float v;
        if (tid < 3)       v = softplusf_(m0[c * 3 + tid]);
        else if (tid < 12) v = softplusf_(m1[c * 9 + (tid - 3)]);
        else if (tid < 21) v = softplusf_(m2[c * 9 + (tid - 12)]);
        else if (tid < 24) v = softplusf_(m3[c * 3 + (tid - 21)]);
        else if (tid < 27) v = b0[c * 3 + (tid - 24)];
        else if (tid < 30) v = b1[c * 3 + (tid - 27)];
        else if (tid < 33) v = b2[c * 3 + (tid - 30)];
        else if (tid < 34) v = b3[c];
        else if (tid < 37) v = tanhf(f0[c * 3 + (tid - 34)]);
        else if (tid < 40) v = tanhf(f1[c * 3 + (tid - 37)]);
        else               v = tanhf(f2[c * 3 + (tid - 40)]);
        p[tid] = v;
    }
}

// ---------------- Fused: 1 block = 1 channel x 4 batch-slabs ----------------
// grid = NCH*4 = 768 blocks (3 blocks/CU, 12 waves/CU). LUT built once per
// block, amortized over 4 slabs. All 16 float4 loads/thread issued before the
// build (HBM latency overlaps build VALU).
// NT store: measured +2.2us win (R7 vs R8 A/B) — write-once stream skips
// L2/L3 allocation. NT load added R9 on the same reasoning (x read once,
// L3 residency destroyed by harness poison fill each iteration anyway).
__global__ __launch_bounds__(256) void eb_fused_kernel(
    const float* __restrict__ x,
    const float* __restrict__ m0, const float* __restrict__ b0,
    const float* __restrict__ m1, const float* __restrict__ b1,
    const float* __restrict__ m2, const float* __restrict__ b2,
    const float* __restrict__ m3, const float* __restrict__ b3,
    const float* __restrict__ f0, const float* __restrict__ f1,
    const float* __restrict__ f2,
    float* __restrict__ out)
{
    __shared__ float p[43];
    __shared__ float f[LUT_N + 1];       // 2.1 KB

    const int c   = blockIdx.x >> 2;     // channel
    const int q   = blockIdx.x & 3;      // which group of 4 batches
    const int tid = threadIdx.x;

    stage_params(p, c, tid, m0, b0, m1, b1, m2, b2, m3, b3, f0, f1, f2);
    __syncthreads();

    const bool g0 = (p[34] != 0.0f) | (p[35] != 0.0f) | (p[36] != 0.0f);
    const bool g1 = (p[37] != 0.0f) | (p[38] != 0.0f) | (p[39] != 0.0f);
    const bool g2 = (p[40] != 0.0f) | (p[41] != 0.0f) | (p[42] != 0.0f);

    // issue ALL streaming loads before the LUT build (latency overlap)
    f4_t v[SLABS_PER_BLOCK * 4];
    size_t bases[SLABS_PER_BLOCK];
#pragma unroll
    for (int s = 0; s < SLABS_PER_BLOCK; ++s) {
        const int b = q * SLABS_PER_BLOCK + s;
        bases[s] = ((size_t)b * NCH + c) * SLAB;
        const f4_t* __restrict__ xin = (const f4_t*)(x + bases[s]);
#pragma unroll
        for (int k = 0; k < 4; ++k)
            v[s * 4 + k] = __builtin_nontemporal_load(&xin[tid + k * 256]);
    }

    // build the 513-node exact table in LDS (~2 evals/thread)
    f[tid]       = element(p, fmaf((float)tid,         LUT_H, LUT_XMIN), g0, g1, g2);
    f[tid + 256] = element(p, fmaf((float)(tid + 256), LUT_H, LUT_XMIN), g0, g1, g2);
    if (tid == 0) {
        f[LUT_N] = element(p, fmaf((float)LUT_N, LUT_H, LUT_XMIN), g0, g1, g2);
    }
    __syncthreads();

#pragma unroll
    for (int s = 0; s < SLABS_PER_BLOCK; ++s) {
        f4_t* __restrict__ o = (f4_t*)(out + bases[s]);
#pragma unroll
        for (int k = 0; k < 4; ++k) {
            const f4_t vv = v[s * 4 + k];
            f4_t r;
            {
                float t = fmaf(vv.x, LUT_INVH, LUT_OFF);
                t = fminf(fmaxf(t, 0.0f), (float)(LUT_N - 1));
                float tf = floorf(t);
                int i = (int)tf;
                r.x = fmaf(t - tf, f[i + 1] - f[i], f[i]);
            }
            {
                float t = fmaf(vv.y, LUT_INVH, LUT_OFF);
                t = fminf(fmaxf(t, 0.0f), (float)(LUT_N - 1));
                float tf = floorf(t);
                int i = (int)tf;
                r.y = fmaf(t - tf, f[i + 1] - f[i], f[i]);
            }
            {
                float t = fmaf(vv.z, LUT_INVH, LUT_OFF);
                t = fminf(fmaxf(t, 0.0f), (float)(LUT_N - 1));
                float tf = floorf(t);
                int i = (int)tf;
                r.z = fmaf(t - tf, f[i + 1] - f[i], f[i]);
            }
            {
                float t = fmaf(vv.w, LUT_INVH, LUT_OFF);
                t = fminf(fmaxf(t, 0.0f), (float)(LUT_N - 1));
                float tf = floorf(t);
                int i = (int)tf;
                r.w = fmaf(t - tf, f[i + 1] - f[i], f[i]);
            }
            __builtin_nontemporal_store(r, &o[tid + k * 256]);
        }
    }
}

extern "C" void kernel_launch(void* const* d_in, const int* in_sizes, int n_in,
                              void* d_out, int out_size, void* d_ws, size_t ws_size,
                              hipStream_t stream) {
    const float* x = (const float*)d_in[0];
    const float *m0, *m1, *m2, *m3, *b0, *b1, *b2, *b3;
    if (in_sizes[2] == 1728) {
        // reference-signature order: x, m0..m3, b0..b3, f0..f2
        m0 = (const float*)d_in[1]; m1 = (const float*)d_in[2];
        m2 = (const float*)d_in[3]; m3 = (const float*)d_in[4];
        b0 = (const float*)d_in[5]; b1 = (const float*)d_in[6];
        b2 = (const float*)d_in[7]; b3 = (const float*)d_in[8];
    } else {
        // setup_inputs dict order: x, m0, b0, m1, b1, m2, b2, m3, b3, f0, f1, f2
        m0 = (const float*)d_in[1]; b0 = (const float*)d_in[2];
        m1 = (const float*)d_in[3]; b1 = (const float*)d_in[4];
        m2 = (const float*)d_in[5]; b2 = (const float*)d_in[6];
        m3 = (const float*)d_in[7]; b3 = (const float*)d_in[8];
    }
    const float* f0 = (const float*)d_in[9];
    const float* f1 = (const float*)d_in[10];
    const float* f2 = (const float*)d_in[11];
    float* out = (float*)d_out;

    const int nblocks = NCH * (16 / SLABS_PER_BLOCK);  // 768; B=16 slabs/channel
    eb_fused_kernel<<<nblocks, 256, 0, stream>>>(x, m0, b0, m1, b1, m2, b2, m3, b3,
                                                 f0, f1, f2, out);
}

// Round 10
// 122.786 us; speedup vs baseline: 1.0243x; 1.0243x over previous
//
#include <hip/hip_runtime.h>
#include <cmath>

#define NCH 192
#define SLAB 4096            // H*W = 64*64, elements per (b,c) row
#define LUT_N 512
#define LUT_XMIN (-8.0f)
#define LUT_H (16.0f / (float)LUT_N)     // 1/32
#define LUT_INVH ((float)LUT_N / 16.0f)  // 32.0
#define LUT_OFF (-(LUT_XMIN) * LUT_INVH) // 256.0
#define SLABS_PER_BLOCK 4

typedef float f4_t __attribute__((ext_vector_type(4)));  // native vector for NT store

__device__ __forceinline__ float sigmoidf_(float x) {
    return 1.0f / (1.0f + __expf(-x));
}

__device__ __forceinline__ float softplusf_(float x) {
    return (x > 20.0f) ? x : log1pf(expf(x));
}

// p layout (43 floats):
// [0:3)  sm0   [3:12) sm1   [12:21) sm2   [21:24) sm3
// [24:27) b0   [27:30) b1   [30:33) b2    [33] b3
// [34:37) tf0  [37:40) tf1  [40:43) tf2
__device__ __forceinline__ float mlp_eval(const float* __restrict__ p, float z,
                                          bool g0, bool g1, bool g2) {
    float t0 = fmaf(p[0], z, p[24]);
    float t1 = fmaf(p[1], z, p[25]);
    float t2 = fmaf(p[2], z, p[26]);
    if (g0) {
        t0 += p[34] * tanhf(t0);
        t1 += p[35] * tanhf(t1);
        t2 += p[36] * tanhf(t2);
    }
    float u0 = fmaf(p[3], t0, fmaf(p[4], t1, fmaf(p[5], t2, p[27])));
    float u1 = fmaf(p[6], t0, fmaf(p[7], t1, fmaf(p[8], t2, p[28])));
    float u2 = fmaf(p[9], t0, fmaf(p[10], t1, fmaf(p[11], t2, p[29])));
    if (g1) {
        u0 += p[37] * tanhf(u0);
        u1 += p[38] * tanhf(u1);
        u2 += p[39] * tanhf(u2);
    }
    float w0 = fmaf(p[12], u0, fmaf(p[13], u1, fmaf(p[14], u2, p[30])));
    float w1 = fmaf(p[15], u0, fmaf(p[16], u1, fmaf(p[17], u2, p[31])));
    float w2 = fmaf(p[18], u0, fmaf(p[19], u1, fmaf(p[20], u2, p[32])));
    if (g2) {
        w0 += p[40] * tanhf(w0);
        w1 += p[41] * tanhf(w1);
        w2 += p[42] * tanhf(w2);
    }
    return fmaf(p[21], w0, fmaf(p[22], w1, fmaf(p[23], w2, p[33])));
}

__device__ __forceinline__ float element(const float* __restrict__ p, float v,
                                         bool g0, bool g1, bool g2) {
    float lo = mlp_eval(p, v - 0.5f, g0, g1, g2);
    float up = mlp_eval(p, v + 0.5f, g0, g1, g2);
    float ssum = lo + up;
    float s = (ssum > 0.0f) ? -1.0f : ((ssum < 0.0f) ? 1.0f : 0.0f);
    float lk = fabsf(sigmoidf_(s * up) - sigmoidf_(s * lo));
    return fmaxf(lk, 1e-6f);
}

__device__ __forceinline__ void stage_params(
    float* p, int c, int tid,
    const float* __restrict__ m0, const float* __restrict__ b0,
    const float* __restrict__ m1, const float* __restrict__ b1,
    const float* __restrict__ m2, const float* __restrict__ b2,
    const float* __restrict__ m3, const float* __restrict__ b3,
    const float* __restrict__ f0, const float* __restrict__ f1,
    const float* __restrict__ f2)
{
    if (tid < 43) {
        float v;
        if (tid < 3)       v = softplusf_(m0[c * 3 + tid]);
        else if (tid < 12) v = softplusf_(m1[c * 9 + (tid - 3)]);
        else if (tid < 21) v = softplusf_(m2[c * 9 + (tid - 12)]);
        else if (tid < 24) v = softplusf_(m3[c * 3 + (tid - 21)]);
        else if (tid < 27) v = b0[c * 3 + (tid - 24)];
        else if (tid < 30) v = b1[c * 3 + (tid - 27)];
        else if (tid < 33) v = b2[c * 3 + (tid - 30)];
        else if (tid < 34) v = b3[c];
        else if (tid < 37) v = tanhf(f0[c * 3 + (tid - 34)]);
        else if (tid < 40) v = tanhf(f1[c * 3 + (tid - 37)]);
        else               v = tanhf(f2[c * 3 + (tid - 40)]);
        p[tid] = v;
    }
}

// ---------------- Fused: 1 block = 1 channel x 4 batch-slabs ----------------
// grid = NCH*4 = 768 blocks (3 blocks/CU, 12 waves/CU). LUT built once per
// block, amortized over 4 slabs. All 16 float4 loads/thread issued before the
// build (HBM latency overlaps build VALU).
// A/B-tested configuration (best of R5..R9 = 121.3 us):
//   loads:  NORMAL  (NT loads: +4.4 us, R9 — nt bypasses L2 line merging)
//   stores: NT      (regular stores: +2.2 us, R8 — dirty-line churn in L2/L3)
//   build:  fused, amortized 4x (per-slab build: +4.2 us, R6; separate kernel: +3.2 us, R5)
__global__ __launch_bounds__(256) void eb_fused_kernel(
    const float* __restrict__ x,
    const float* __restrict__ m0, const float* __restrict__ b0,
    const float* __restrict__ m1, const float* __restrict__ b1,
    const float* __restrict__ m2, const float* __restrict__ b2,
    const float* __restrict__ m3, const float* __restrict__ b3,
    const float* __restrict__ f0, const float* __restrict__ f1,
    const float* __restrict__ f2,
    float* __restrict__ out)
{
    __shared__ float p[43];
    __shared__ float f[LUT_N + 1];       // 2.1 KB

    const int c   = blockIdx.x >> 2;     // channel
    const int q   = blockIdx.x & 3;      // which group of 4 batches
    const int tid = threadIdx.x;

    stage_params(p, c, tid, m0, b0, m1, b1, m2, b2, m3, b3, f0, f1, f2);
    __syncthreads();

    const bool g0 = (p[34] != 0.0f) | (p[35] != 0.0f) | (p[36] != 0.0f);
    const bool g1 = (p[37] != 0.0f) | (p[38] != 0.0f) | (p[39] != 0.0f);
    const bool g2 = (p[40] != 0.0f) | (p[41] != 0.0f) | (p[42] != 0.0f);

    // issue ALL streaming loads before the LUT build (latency overlap)
    float4 v[SLABS_PER_BLOCK * 4];
    size_t bases[SLABS_PER_BLOCK];
#pragma unroll
    for (int s = 0; s < SLABS_PER_BLOCK; ++s) {
        const int b = q * SLABS_PER_BLOCK + s;
        bases[s] = ((size_t)b * NCH + c) * SLAB;
        const float4* __restrict__ xin = (const float4*)(x + bases[s]);
#pragma unroll
        for (int k = 0; k < 4; ++k) v[s * 4 + k] = xin[tid + k * 256];
    }

    // build the 513-node exact table in LDS (~2 evals/thread)
    f[tid]       = element(p, fmaf((float)tid,         LUT_H, LUT_XMIN), g0, g1, g2);
    f[tid + 256] = element(p, fmaf((float)(tid + 256), LUT_H, LUT_XMIN), g0, g1, g2);
    if (tid == 0) {
        f[LUT_N] = element(p, fmaf((float)LUT_N, LUT_H, LUT_XMIN), g0, g1, g2);
    }
    __syncthreads();

#pragma unroll
    for (int s = 0; s < SLABS_PER_BLOCK; ++s) {
        f4_t* __restrict__ o = (f4_t*)(out + bases[s]);
#pragma unroll
        for (int k = 0; k < 4; ++k) {
            const float4 vv = v[s * 4 + k];
            f4_t r;
            {
                float t = fmaf(vv.x, LUT_INVH, LUT_OFF);
                t = fminf(fmaxf(t, 0.0f), (float)(LUT_N - 1));
                float tf = floorf(t);
                int i = (int)tf;
                r.x = fmaf(t - tf, f[i + 1] - f[i], f[i]);
            }
            {
                float t = fmaf(vv.y, LUT_INVH, LUT_OFF);
                t = fminf(fmaxf(t, 0.0f), (float)(LUT_N - 1));
                float tf = floorf(t);
                int i = (int)tf;
                r.y = fmaf(t - tf, f[i + 1] - f[i], f[i]);
            }
            {
                float t = fmaf(vv.z, LUT_INVH, LUT_OFF);
                t = fminf(fmaxf(t, 0.0f), (float)(LUT_N - 1));
                float tf = floorf(t);
                int i = (int)tf;
                r.z = fmaf(t - tf, f[i + 1] - f[i], f[i]);
            }
            {
                float t = fmaf(vv.w, LUT_INVH, LUT_OFF);
                t = fminf(fmaxf(t, 0.0f), (float)(LUT_N - 1));
                float tf = floorf(t);
                int i = (int)tf;
                r.w = fmaf(t - tf, f[i + 1] - f[i], f[i]);
            }
            // output is write-once, never re-read: keep it out of L2/L3
            __builtin_nontemporal_store(r, &o[tid + k * 256]);
        }
    }
}

extern "C" void kernel_launch(void* const* d_in, const int* in_sizes, int n_in,
                              void* d_out, int out_size, void* d_ws, size_t ws_size,
                              hipStream_t stream) {
    const float* x = (const float*)d_in[0];
    const float *m0, *m1, *m2, *m3, *b0, *b1, *b2, *b3;
    if (in_sizes[2] == 1728) {
        // reference-signature order: x, m0..m3, b0..b3, f0..f2
        m0 = (const float*)d_in[1]; m1 = (const float*)d_in[2];
        m2 = (const float*)d_in[3]; m3 = (const float*)d_in[4];
        b0 = (const float*)d_in[5]; b1 = (const float*)d_in[6];
        b2 = (const float*)d_in[7]; b3 = (const float*)d_in[8];
    } else {
        // setup_inputs dict order: x, m0, b0, m1, b1, m2, b2, m3, b3, f0, f1, f2
        m0 = (const float*)d_in[1]; b0 = (const float*)d_in[2];
        m1 = (const float*)d_in[3]; b1 = (const float*)d_in[4];
        m2 = (const float*)d_in[5]; b2 = (const float*)d_in[6];
        m3 = (const float*)d_in[7]; b3 = (const float*)d_in[8];
    }
    const float* f0 = (const float*)d_in[9];
    const float* f1 = (const float*)d_in[10];
    const float* f2 = (const float*)d_in[11];
    float* out = (float*)d_out;

    const int nblocks = NCH * (16 / SLABS_PER_BLOCK);  // 768; B=16 slabs/channel
    eb_fused_kernel<<<nblocks, 256, 0, stream>>>(x, m0, b0, m1, b1, m2, b2, m3, b3,
                                                 f0, f1, f2, out);
}